// Round 1
// baseline (1268.771 us; speedup 1.0000x reference)
//
#include <hip/hip_runtime.h>

// GNN (5 layers sparse msg-passing + dense+relu) -> gather -> concat -> FC over 50000 entities.
// Strategy: build CSR once per call (hist/scan/scatter), wave-per-row aggregate,
// register-tiled fp32 GEMMs. All fp32 (correctness baseline).

#define N_NODES 50000
#define N_EDGES 800000
#define D 128
#define N_LAYERS 5
#define N_ENT 50000
#define BATCH 1024
#define KDIM 256  // 2*D

__global__ void zero_i32(int* __restrict__ p, int n) {
  int i = blockIdx.x * blockDim.x + threadIdx.x;
  if (i < n) p[i] = 0;
}

__global__ void hist_kernel(const int* __restrict__ rows, int* __restrict__ counts) {
  int i = blockIdx.x * blockDim.x + threadIdx.x;
  int stride = gridDim.x * blockDim.x;
  for (; i < N_EDGES; i += stride) atomicAdd(&counts[rows[i]], 1);
}

// single block; exclusive scan of counts[N_NODES] -> row_ptr, cursor
__global__ __launch_bounds__(1024) void scan_kernel(const int* __restrict__ counts,
                                                    int* __restrict__ row_ptr,
                                                    int* __restrict__ cursor) {
  __shared__ int wsum[16];
  int t = threadIdx.x;
  int lane = t & 63, wid = t >> 6;
  int carry = 0;  // live in thread 0 only
  for (int base = 0; base < N_NODES; base += 1024) {
    int i = base + t;
    int v = (i < N_NODES) ? counts[i] : 0;
    int s = v;
#pragma unroll
    for (int off = 1; off < 64; off <<= 1) {
      int u = __shfl_up(s, off, 64);
      if (lane >= off) s += u;
    }
    if (lane == 63) wsum[wid] = s;
    __syncthreads();
    if (t == 0) {
      int run = carry;
#pragma unroll
      for (int w = 0; w < 16; ++w) { int tmp = wsum[w]; wsum[w] = run; run += tmp; }
      carry = run;
    }
    __syncthreads();
    if (i < N_NODES) {
      int excl = wsum[wid] + s - v;
      row_ptr[i] = excl;
      cursor[i] = excl;
    }
    __syncthreads();  // WAR: protect wsum before next chunk
  }
  if (t == 0) row_ptr[N_NODES] = carry;
}

__global__ void scatter_kernel(const int* __restrict__ rows, const int* __restrict__ cols,
                               const float* __restrict__ vals, int* __restrict__ cursor,
                               int* __restrict__ col_s, float* __restrict__ val_s) {
  int i = blockIdx.x * blockDim.x + threadIdx.x;
  int stride = gridDim.x * blockDim.x;
  for (; i < N_EDGES; i += stride) {
    int r = rows[i];
    int pos = atomicAdd(&cursor[r], 1);
    col_s[pos] = cols[i];
    val_s[pos] = vals[i];
  }
}

// one wave per row: agg[r][:] = sum_e val[e] * x[col[e]][:]
__global__ __launch_bounds__(256) void agg_kernel(const float* __restrict__ x,
                                                  const int* __restrict__ row_ptr,
                                                  const int* __restrict__ cols,
                                                  const float* __restrict__ vals,
                                                  float* __restrict__ agg) {
  int wid = threadIdx.x >> 6;
  int lane = threadIdx.x & 63;
  int r = blockIdx.x * 4 + wid;
  if (r >= N_NODES) return;
  int e0 = row_ptr[r], e1 = row_ptr[r + 1];
  float ax = 0.f, ay = 0.f;
  for (int e = e0; e < e1; ++e) {
    int c = cols[e];
    float v = vals[e];
    const float2 xv = *(const float2*)&x[c * D + lane * 2];
    ax = fmaf(v, xv.x, ax);
    ay = fmaf(v, xv.y, ay);
  }
  float2 o = {ax, ay};
  *(float2*)&agg[r * D + lane * 2] = o;
}

// Y[r][:] = relu(X[r][:] @ W + b); block: 64 rows x 128 cols, thread: 4 rows x 8 cols
__global__ __launch_bounds__(256) void gemm_layer(const float* __restrict__ X,
                                                  const float* __restrict__ W,
                                                  const float* __restrict__ bias,
                                                  float* __restrict__ Y) {
  __shared__ float xT[D][65];  // transposed tile, padded
  int t = threadIdx.x;
  int r0 = blockIdx.x * 64;
#pragma unroll
  for (int it = 0; it < 8; ++it) {
    int fid = it * 256 + t;   // 0..2047 over 64 rows x 32 float4
    int rl = fid >> 5;
    int kq = fid & 31;
    float4 g = {0.f, 0.f, 0.f, 0.f};
    int r = r0 + rl;
    if (r < N_NODES) g = *(const float4*)&X[r * D + kq * 4];
    xT[kq * 4 + 0][rl] = g.x;
    xT[kq * 4 + 1][rl] = g.y;
    xT[kq * 4 + 2][rl] = g.z;
    xT[kq * 4 + 3][rl] = g.w;
  }
  __syncthreads();
  int tx = t & 15;   // col group: cols tx*8 .. tx*8+7
  int ty = t >> 4;   // rows r0 + ty + {0,16,32,48}
  float acc[4][8] = {};
#pragma unroll 4
  for (int k = 0; k < D; ++k) {
    float4 w0 = *(const float4*)&W[k * D + tx * 8];
    float4 w1 = *(const float4*)&W[k * D + tx * 8 + 4];
    float wv[8] = {w0.x, w0.y, w0.z, w0.w, w1.x, w1.y, w1.z, w1.w};
    float xv[4];
#pragma unroll
    for (int i = 0; i < 4; ++i) xv[i] = xT[k][ty + 16 * i];
#pragma unroll
    for (int i = 0; i < 4; ++i)
#pragma unroll
      for (int j = 0; j < 8; ++j) acc[i][j] = fmaf(xv[i], wv[j], acc[i][j]);
  }
  float bb[8];
#pragma unroll
  for (int j = 0; j < 8; ++j) bb[j] = bias[tx * 8 + j];
#pragma unroll
  for (int i = 0; i < 4; ++i) {
    int r = r0 + ty + 16 * i;
    if (r < N_NODES) {
      float4 o0 = {fmaxf(acc[i][0] + bb[0], 0.f), fmaxf(acc[i][1] + bb[1], 0.f),
                   fmaxf(acc[i][2] + bb[2], 0.f), fmaxf(acc[i][3] + bb[3], 0.f)};
      float4 o1 = {fmaxf(acc[i][4] + bb[4], 0.f), fmaxf(acc[i][5] + bb[5], 0.f),
                   fmaxf(acc[i][6] + bb[6], 0.f), fmaxf(acc[i][7] + bb[7], 0.f)};
      *(float4*)&Y[r * D + tx * 8] = o0;
      *(float4*)&Y[r * D + tx * 8 + 4] = o1;
    }
  }
}

// embT[d][b]: d<128 -> x[head_idx[b]][d], else rel_table[rel_ids[b]][d-128]
__global__ __launch_bounds__(256) void gather_kernel(const float* __restrict__ xfin,
                                                     const float* __restrict__ rel_table,
                                                     const int* __restrict__ head_idx,
                                                     const int* __restrict__ rel_ids,
                                                     float* __restrict__ embT) {
  int dd = blockIdx.x;  // 0..255
  int t = threadIdx.x;
#pragma unroll
  for (int j = 0; j < 4; ++j) {
    int b = t + j * 256;
    float v;
    if (dd < D) v = xfin[head_idx[b] * D + dd];
    else        v = rel_table[rel_ids[b] * D + (dd - D)];
    embT[dd * BATCH + b] = v;
  }
}

// logits = embed @ fc_W + fc_b. block: 64 b-rows x 256 n-cols; thread: 16 b x 4 n
__global__ __launch_bounds__(256) void fc_kernel(const float* __restrict__ embT,
                                                 const float* __restrict__ fcW,
                                                 const float* __restrict__ fcb,
                                                 float* __restrict__ out) {
  __shared__ float eT[KDIM][64];  // [k][b] tile, 64 KiB
  int t = threadIdx.x;
  int n0 = blockIdx.x * 256;
  int b0 = blockIdx.y * 64;
#pragma unroll
  for (int it = 0; it < 16; ++it) {
    int fid = it * 256 + t;  // 0..4095 over 256 rows x 16 float4
    int k = fid >> 4;
    int q = fid & 15;
    float4 g = *(const float4*)&embT[k * BATCH + b0 + q * 4];
    *(float4*)&eT[k][q * 4] = g;
  }
  __syncthreads();
  int tx = t & 63;  // n-col group: n0 + tx*4
  int ty = t >> 6;  // wave id -> b rows ty*16..ty*16+15 (LDS reads are wave-broadcast)
  int n = n0 + tx * 4;
  bool nok = (n < N_ENT);
  float acc[16][4] = {};
  for (int k = 0; k < KDIM; ++k) {
    float4 w4 = {0.f, 0.f, 0.f, 0.f};
    if (nok) w4 = *(const float4*)&fcW[(size_t)k * N_ENT + n];
    float ww[4] = {w4.x, w4.y, w4.z, w4.w};
    float ee[16];
#pragma unroll
    for (int q = 0; q < 4; ++q) {
      float4 e4 = *(const float4*)&eT[k][ty * 16 + q * 4];
      ee[q * 4 + 0] = e4.x; ee[q * 4 + 1] = e4.y; ee[q * 4 + 2] = e4.z; ee[q * 4 + 3] = e4.w;
    }
#pragma unroll
    for (int i = 0; i < 16; ++i)
#pragma unroll
      for (int j = 0; j < 4; ++j) acc[i][j] = fmaf(ee[i], ww[j], acc[i][j]);
  }
  if (nok) {
    float4 b4 = *(const float4*)&fcb[n];
    float bb[4] = {b4.x, b4.y, b4.z, b4.w};
#pragma unroll
    for (int i = 0; i < 16; ++i) {
      int b = b0 + ty * 16 + i;
      float4 o = {acc[i][0] + bb[0], acc[i][1] + bb[1], acc[i][2] + bb[2], acc[i][3] + bb[3]};
      *(float4*)&out[(size_t)b * N_ENT + n] = o;
    }
  }
}

extern "C" void kernel_launch(void* const* d_in, const int* in_sizes, int n_in,
                              void* d_out, int out_size, void* d_ws, size_t ws_size,
                              hipStream_t stream) {
  const float* entity    = (const float*)d_in[0];
  const float* edge_val  = (const float*)d_in[1];
  const float* gnn_W     = (const float*)d_in[2];
  const float* gnn_b     = (const float*)d_in[3];
  const float* rel_table = (const float*)d_in[4];
  const float* fc_W      = (const float*)d_in[5];
  const float* fc_b      = (const float*)d_in[6];
  const int* edge_row    = (const int*)d_in[7];
  const int* edge_col    = (const int*)d_in[8];
  const int* head_idx    = (const int*)d_in[9];
  const int* rel_ids     = (const int*)d_in[10];
  float* out = (float*)d_out;

  char* ws = (char*)d_ws;
  size_t off = 0;
  auto alloc = [&](size_t bytes) -> void* {
    void* p = ws + off;
    off = (off + bytes + 255) & ~(size_t)255;
    return p;
  };
  int* counts   = (int*)alloc((size_t)N_NODES * 4);
  int* row_ptr  = (int*)alloc((size_t)(N_NODES + 1) * 4);
  int* cursor   = (int*)alloc((size_t)N_NODES * 4);
  int* col_s    = (int*)alloc((size_t)N_EDGES * 4);
  float* val_s  = (float*)alloc((size_t)N_EDGES * 4);
  float* agg    = (float*)alloc((size_t)N_NODES * D * 4);
  float* xbuf   = (float*)alloc((size_t)N_NODES * D * 4);
  float* embT   = (float*)alloc((size_t)KDIM * BATCH * 4);

  // CSR build (row structure is layer-invariant)
  zero_i32<<<(N_NODES + 255) / 256, 256, 0, stream>>>(counts, N_NODES);
  hist_kernel<<<1024, 256, 0, stream>>>(edge_row, counts);
  scan_kernel<<<1, 1024, 0, stream>>>(counts, row_ptr, cursor);
  scatter_kernel<<<1024, 256, 0, stream>>>(edge_row, edge_col, edge_val, cursor, col_s, val_s);

  // 5 GNN layers
  for (int layer = 0; layer < N_LAYERS; ++layer) {
    const float* xin = (layer == 0) ? entity : xbuf;
    agg_kernel<<<N_NODES / 4, 256, 0, stream>>>(xin, row_ptr, col_s, val_s, agg);
    gemm_layer<<<(N_NODES + 63) / 64, 256, 0, stream>>>(agg, gnn_W + (size_t)layer * D * D,
                                                        gnn_b + (size_t)layer * D, xbuf);
  }

  // gather + concat (stored transposed [256][1024] for FC staging)
  gather_kernel<<<KDIM, 256, 0, stream>>>(xbuf, rel_table, head_idx, rel_ids, embT);

  // FC: [1024,256] @ [256,50000] + b
  dim3 fcg((N_ENT + 255) / 256, BATCH / 64);
  fc_kernel<<<fcg, 256, 0, stream>>>(embT, fc_W, fc_b, out);
}

// Round 2
// 914.995 us; speedup vs baseline: 1.3866x; 1.3866x over previous
//
#include <hip/hip_runtime.h>

// GNN (5 layers sparse msg-passing + dense+relu) -> gather -> concat -> FC over 50000 entities.
// CSR built once per call; wave-per-row aggregate; fp32 GNN GEMMs;
// FC = bf16 MFMA GEMM (16x16x32), W transposed+converted once per call.

#define N_NODES 50000
#define N_EDGES 800000
#define D 128
#define N_LAYERS 5
#define N_ENT 50000
#define BATCH 1024
#define KDIM 256  // 2*D

typedef __attribute__((ext_vector_type(8))) __bf16 bf16x8;
typedef __attribute__((ext_vector_type(4))) float f32x4;

__device__ inline unsigned short f2bf(float x) {
  unsigned int u = __float_as_uint(x);
  unsigned int r = (u + 0x7FFFu + ((u >> 16) & 1u)) >> 16;  // RNE
  return (unsigned short)r;
}

__global__ void zero_i32(int* __restrict__ p, int n) {
  int i = blockIdx.x * blockDim.x + threadIdx.x;
  if (i < n) p[i] = 0;
}

__global__ void hist_kernel(const int* __restrict__ rows, int* __restrict__ counts) {
  int i = blockIdx.x * blockDim.x + threadIdx.x;
  int stride = gridDim.x * blockDim.x;
  for (; i < N_EDGES; i += stride) atomicAdd(&counts[rows[i]], 1);
}

// single block; exclusive scan of counts[N_NODES] -> row_ptr, cursor
__global__ __launch_bounds__(1024) void scan_kernel(const int* __restrict__ counts,
                                                    int* __restrict__ row_ptr,
                                                    int* __restrict__ cursor) {
  __shared__ int wsum[16];
  int t = threadIdx.x;
  int lane = t & 63, wid = t >> 6;
  int carry = 0;  // live in thread 0 only
  for (int base = 0; base < N_NODES; base += 1024) {
    int i = base + t;
    int v = (i < N_NODES) ? counts[i] : 0;
    int s = v;
#pragma unroll
    for (int off = 1; off < 64; off <<= 1) {
      int u = __shfl_up(s, off, 64);
      if (lane >= off) s += u;
    }
    if (lane == 63) wsum[wid] = s;
    __syncthreads();
    if (t == 0) {
      int run = carry;
#pragma unroll
      for (int w = 0; w < 16; ++w) { int tmp = wsum[w]; wsum[w] = run; run += tmp; }
      carry = run;
    }
    __syncthreads();
    if (i < N_NODES) {
      int excl = wsum[wid] + s - v;
      row_ptr[i] = excl;
      cursor[i] = excl;
    }
    __syncthreads();  // WAR: protect wsum before next chunk
  }
  if (t == 0) row_ptr[N_NODES] = carry;
}

__global__ void scatter_kernel(const int* __restrict__ rows, const int* __restrict__ cols,
                               const float* __restrict__ vals, int* __restrict__ cursor,
                               int* __restrict__ col_s, float* __restrict__ val_s) {
  int i = blockIdx.x * blockDim.x + threadIdx.x;
  int stride = gridDim.x * blockDim.x;
  for (; i < N_EDGES; i += stride) {
    int r = rows[i];
    int pos = atomicAdd(&cursor[r], 1);
    col_s[pos] = cols[i];
    val_s[pos] = vals[i];
  }
}

// one wave per row: agg[r][:] = sum_e val[e] * x[col[e]][:]
__global__ __launch_bounds__(256) void agg_kernel(const float* __restrict__ x,
                                                  const int* __restrict__ row_ptr,
                                                  const int* __restrict__ cols,
                                                  const float* __restrict__ vals,
                                                  float* __restrict__ agg) {
  int wid = threadIdx.x >> 6;
  int lane = threadIdx.x & 63;
  int r = blockIdx.x * 4 + wid;
  if (r >= N_NODES) return;
  int e0 = row_ptr[r], e1 = row_ptr[r + 1];
  float ax = 0.f, ay = 0.f;
  for (int e = e0; e < e1; ++e) {
    int c = cols[e];
    float v = vals[e];
    const float2 xv = *(const float2*)&x[c * D + lane * 2];
    ax = fmaf(v, xv.x, ax);
    ay = fmaf(v, xv.y, ay);
  }
  float2 o = {ax, ay};
  *(float2*)&agg[r * D + lane * 2] = o;
}

// Y[r][:] = relu(X[r][:] @ W + b); block: 64 rows x 128 cols, thread: 4 rows x 8 cols
__global__ __launch_bounds__(256) void gemm_layer(const float* __restrict__ X,
                                                  const float* __restrict__ W,
                                                  const float* __restrict__ bias,
                                                  float* __restrict__ Y) {
  __shared__ float xT[D][65];  // transposed tile, padded
  int t = threadIdx.x;
  int r0 = blockIdx.x * 64;
#pragma unroll
  for (int it = 0; it < 8; ++it) {
    int fid = it * 256 + t;   // 0..2047 over 64 rows x 32 float4
    int rl = fid >> 5;
    int kq = fid & 31;
    float4 g = {0.f, 0.f, 0.f, 0.f};
    int r = r0 + rl;
    if (r < N_NODES) g = *(const float4*)&X[r * D + kq * 4];
    xT[kq * 4 + 0][rl] = g.x;
    xT[kq * 4 + 1][rl] = g.y;
    xT[kq * 4 + 2][rl] = g.z;
    xT[kq * 4 + 3][rl] = g.w;
  }
  __syncthreads();
  int tx = t & 15;   // col group: cols tx*8 .. tx*8+7
  int ty = t >> 4;   // rows r0 + ty + {0,16,32,48}
  float acc[4][8] = {};
#pragma unroll 4
  for (int k = 0; k < D; ++k) {
    float4 w0 = *(const float4*)&W[k * D + tx * 8];
    float4 w1 = *(const float4*)&W[k * D + tx * 8 + 4];
    float wv[8] = {w0.x, w0.y, w0.z, w0.w, w1.x, w1.y, w1.z, w1.w};
    float xv[4];
#pragma unroll
    for (int i = 0; i < 4; ++i) xv[i] = xT[k][ty + 16 * i];
#pragma unroll
    for (int i = 0; i < 4; ++i)
#pragma unroll
      for (int j = 0; j < 8; ++j) acc[i][j] = fmaf(xv[i], wv[j], acc[i][j]);
  }
  float bb[8];
#pragma unroll
  for (int j = 0; j < 8; ++j) bb[j] = bias[tx * 8 + j];
#pragma unroll
  for (int i = 0; i < 4; ++i) {
    int r = r0 + ty + 16 * i;
    if (r < N_NODES) {
      float4 o0 = {fmaxf(acc[i][0] + bb[0], 0.f), fmaxf(acc[i][1] + bb[1], 0.f),
                   fmaxf(acc[i][2] + bb[2], 0.f), fmaxf(acc[i][3] + bb[3], 0.f)};
      float4 o1 = {fmaxf(acc[i][4] + bb[4], 0.f), fmaxf(acc[i][5] + bb[5], 0.f),
                   fmaxf(acc[i][6] + bb[6], 0.f), fmaxf(acc[i][7] + bb[7], 0.f)};
      *(float4*)&Y[r * D + tx * 8] = o0;
      *(float4*)&Y[r * D + tx * 8 + 4] = o1;
    }
  }
}

// transpose+convert fc_W [KDIM][N_ENT] f32 -> Wt [N_ENT][KDIM] bf16
// grid: (N_ENT/256, KDIM/8); thread -> (n, kg)
__global__ __launch_bounds__(256) void wt_kernel(const float* __restrict__ fcW,
                                                 unsigned short* __restrict__ Wt) {
  int n = blockIdx.x * 256 + threadIdx.x;
  int k0 = blockIdx.y * 8;
  if (n >= N_ENT) return;
  unsigned short v[8];
#pragma unroll
  for (int e = 0; e < 8; ++e) v[e] = f2bf(fcW[(size_t)(k0 + e) * N_ENT + n]);
  typedef __attribute__((ext_vector_type(8))) unsigned short u16x8;
  u16x8 pk;
#pragma unroll
  for (int e = 0; e < 8; ++e) pk[e] = v[e];
  *(u16x8*)&Wt[(size_t)n * KDIM + k0] = pk;
}

// ebf[b][k] bf16: k<128 -> x[head_idx[b]][k], else rel_table[rel_ids[b]][k-128]
__global__ __launch_bounds__(256) void gather_bf16(const float* __restrict__ xfin,
                                                   const float* __restrict__ rel_table,
                                                   const int* __restrict__ head_idx,
                                                   const int* __restrict__ rel_ids,
                                                   unsigned short* __restrict__ ebf) {
  int b = blockIdx.x;
  int k = threadIdx.x;
  float v;
  if (k < D) v = xfin[head_idx[b] * D + k];
  else       v = rel_table[rel_ids[b] * D + (k - D)];
  ebf[b * KDIM + k] = f2bf(v);
}

// FC: out[b][n] = sum_k ebf[b][k]*Wt[n][k] + fcb[n]
// block 256 thr = 4 waves; block tile 64 b x 256 n; wave tile 64 b x 64 n
__global__ __launch_bounds__(256) void fc_mfma(const unsigned short* __restrict__ ebf,
                                               const unsigned short* __restrict__ Wt,
                                               const float* __restrict__ fcb,
                                               float* __restrict__ out) {
  int t = threadIdx.x;
  int lane = t & 63;
  int wave = t >> 6;
  int b0 = blockIdx.y * 64;
  int n_wave = blockIdx.x * 256 + wave * 64;

  int l16 = lane & 15;
  int lq = lane >> 4;  // 0..3

  f32x4 acc[4][4];
#pragma unroll
  for (int m = 0; m < 4; ++m)
#pragma unroll
    for (int nt = 0; nt < 4; ++nt) acc[m][nt] = (f32x4){0.f, 0.f, 0.f, 0.f};

  // per-lane row bases
  const unsigned short* aBase = ebf + (b0 + l16) * KDIM + lq * 8;
  const unsigned short* bBase[4];
#pragma unroll
  for (int nt = 0; nt < 4; ++nt) {
    int n = n_wave + nt * 16 + l16;
    int nn = n < N_ENT ? n : N_ENT - 1;  // clamp; stores guarded below
    bBase[nt] = Wt + (size_t)nn * KDIM + lq * 8;
  }

#pragma unroll
  for (int kk = 0; kk < 8; ++kk) {
    bf16x8 a[4], bb[4];
#pragma unroll
    for (int m = 0; m < 4; ++m)
      a[m] = *(const bf16x8*)(aBase + m * 16 * KDIM + kk * 32);
#pragma unroll
    for (int nt = 0; nt < 4; ++nt)
      bb[nt] = *(const bf16x8*)(bBase[nt] + kk * 32);
#pragma unroll
    for (int m = 0; m < 4; ++m)
#pragma unroll
      for (int nt = 0; nt < 4; ++nt)
        acc[m][nt] = __builtin_amdgcn_mfma_f32_16x16x32_bf16(a[m], bb[nt], acc[m][nt], 0, 0, 0);
  }

#pragma unroll
  for (int nt = 0; nt < 4; ++nt) {
    int n = n_wave + nt * 16 + l16;
    if (n >= N_ENT) continue;
    float bv = fcb[n];
#pragma unroll
    for (int m = 0; m < 4; ++m) {
      int brow = b0 + m * 16 + lq * 4;
#pragma unroll
      for (int r = 0; r < 4; ++r)
        out[(size_t)(brow + r) * N_ENT + n] = acc[m][nt][r] + bv;
    }
  }
}

extern "C" void kernel_launch(void* const* d_in, const int* in_sizes, int n_in,
                              void* d_out, int out_size, void* d_ws, size_t ws_size,
                              hipStream_t stream) {
  const float* entity    = (const float*)d_in[0];
  const float* edge_val  = (const float*)d_in[1];
  const float* gnn_W     = (const float*)d_in[2];
  const float* gnn_b     = (const float*)d_in[3];
  const float* rel_table = (const float*)d_in[4];
  const float* fc_W      = (const float*)d_in[5];
  const float* fc_b      = (const float*)d_in[6];
  const int* edge_row    = (const int*)d_in[7];
  const int* edge_col    = (const int*)d_in[8];
  const int* head_idx    = (const int*)d_in[9];
  const int* rel_ids     = (const int*)d_in[10];
  float* out = (float*)d_out;

  char* ws = (char*)d_ws;
  size_t off = 0;
  auto alloc = [&](size_t bytes) -> void* {
    void* p = ws + off;
    off = (off + bytes + 255) & ~(size_t)255;
    return p;
  };
  int* counts   = (int*)alloc((size_t)N_NODES * 4);
  int* row_ptr  = (int*)alloc((size_t)(N_NODES + 1) * 4);
  int* cursor   = (int*)alloc((size_t)N_NODES * 4);
  int* col_s    = (int*)alloc((size_t)N_EDGES * 4);
  float* val_s  = (float*)alloc((size_t)N_EDGES * 4);
  float* agg    = (float*)alloc((size_t)N_NODES * D * 4);   // reused as Wt after layers
  float* xbuf   = (float*)alloc((size_t)N_NODES * D * 4);
  unsigned short* ebf = (unsigned short*)alloc((size_t)BATCH * KDIM * 2);

  // Wt bf16 [N_ENT][KDIM] aliases agg (agg dead after the last gemm_layer)
  unsigned short* Wt = (unsigned short*)agg;  // 50000*256*2 = 25.6 MB == agg size

  // CSR build (row structure is layer-invariant)
  zero_i32<<<(N_NODES + 255) / 256, 256, 0, stream>>>(counts, N_NODES);
  hist_kernel<<<1024, 256, 0, stream>>>(edge_row, counts);
  scan_kernel<<<1, 1024, 0, stream>>>(counts, row_ptr, cursor);
  scatter_kernel<<<1024, 256, 0, stream>>>(edge_row, edge_col, edge_val, cursor, col_s, val_s);

  // 5 GNN layers
  for (int layer = 0; layer < N_LAYERS; ++layer) {
    const float* xin = (layer == 0) ? entity : xbuf;
    agg_kernel<<<N_NODES / 4, 256, 0, stream>>>(xin, row_ptr, col_s, val_s, agg);
    gemm_layer<<<(N_NODES + 63) / 64, 256, 0, stream>>>(agg, gnn_W + (size_t)layer * D * D,
                                                        gnn_b + (size_t)layer * D, xbuf);
  }

  // W transpose+bf16 (into agg's space) and embed gather+concat in bf16
  dim3 wtg((N_ENT + 255) / 256, KDIM / 8);
  wt_kernel<<<wtg, 256, 0, stream>>>(fc_W, Wt);
  gather_bf16<<<BATCH, KDIM, 0, stream>>>(xbuf, rel_table, head_idx, rel_ids, ebf);

  // FC: [1024,256] @ [256,50000] + b via bf16 MFMA
  dim3 fcg((N_ENT + 255) / 256, BATCH / 64);
  fc_mfma<<<fcg, 256, 0, stream>>>(ebf, Wt, fc_b, out);
}

// Round 3
// 745.187 us; speedup vs baseline: 1.7026x; 1.2279x over previous
//
#include <hip/hip_runtime.h>

// GNN (5 layers sparse msg-passing + dense+relu) -> gather -> concat -> FC over 50000 entities.
// CSR built once per call (hist + distributed scan + scatter).
// Node features propagated in bf16 (halves gather traffic); aggregation + GEMM accumulate fp32.
// FC = bf16 MFMA GEMM (16x16x32), 256b x 256n block tile, W transposed+converted once per call.

#define N_NODES 50000
#define N_EDGES 800000
#define D 128
#define N_LAYERS 5
#define N_ENT 50000
#define BATCH 1024
#define KDIM 256  // 2*D
#define SCAN_BLOCKS ((N_NODES + 255) / 256)  // 196

typedef __attribute__((ext_vector_type(8))) __bf16 bf16x8;
typedef __attribute__((ext_vector_type(4))) float f32x4;
typedef __attribute__((ext_vector_type(8))) unsigned short u16x8;

__device__ inline unsigned short f2bf(float x) {
  unsigned int u = __float_as_uint(x);
  unsigned int r = (u + 0x7FFFu + ((u >> 16) & 1u)) >> 16;  // RNE
  return (unsigned short)r;
}
__device__ inline float bf2f(unsigned short b) {
  return __uint_as_float(((unsigned int)b) << 16);
}

__global__ void zero_i32(int* __restrict__ p, int n) {
  int i = blockIdx.x * blockDim.x + threadIdx.x;
  if (i < n) p[i] = 0;
}

__global__ void hist_kernel(const int* __restrict__ rows, int* __restrict__ counts) {
  int i = blockIdx.x * blockDim.x + threadIdx.x;
  int stride = gridDim.x * blockDim.x;
  for (; i < N_EDGES; i += stride) atomicAdd(&counts[rows[i]], 1);
}

// exclusive scan within a 256-thread block; returns exclusive prefix, *tot = block total
__device__ inline int block_exscan256(int v, int* wsum, int* tot) {
  int t = threadIdx.x, lane = t & 63, wid = t >> 6;
  int s = v;
#pragma unroll
  for (int off = 1; off < 64; off <<= 1) {
    int u = __shfl_up(s, off, 64);
    if (lane >= off) s += u;
  }
  if (lane == 63) wsum[wid] = s;
  __syncthreads();
  if (t == 0) {
    int run = 0;
#pragma unroll
    for (int w = 0; w < 4; ++w) { int tmp = wsum[w]; wsum[w] = run; run += tmp; }
    wsum[4] = run;
  }
  __syncthreads();
  *tot = wsum[4];
  return wsum[wid] + s - v;
}

// pass 1: per-block exclusive scan -> row_ptr (block-local), block totals -> bsum
__global__ __launch_bounds__(256) void scan1_kernel(const int* __restrict__ counts,
                                                    int* __restrict__ row_ptr,
                                                    int* __restrict__ bsum) {
  __shared__ int wsum[5];
  int i = blockIdx.x * 256 + threadIdx.x;
  int v = (i < N_NODES) ? counts[i] : 0;
  int tot;
  int ex = block_exscan256(v, wsum, &tot);
  if (i < N_NODES) row_ptr[i] = ex;
  if (threadIdx.x == 0) bsum[blockIdx.x] = tot;
}

// pass 2: single block scans the 196 block totals in place
__global__ __launch_bounds__(256) void scan2_kernel(int* __restrict__ bsum) {
  __shared__ int wsum[5];
  int t = threadIdx.x;
  int v = (t < SCAN_BLOCKS) ? bsum[t] : 0;
  int tot;
  int ex = block_exscan256(v, wsum, &tot);
  if (t < SCAN_BLOCKS) bsum[t] = ex;
}

// pass 3: add block offsets; init cursor; write row_ptr[N]
__global__ __launch_bounds__(256) void scan3_kernel(const int* __restrict__ counts,
                                                    const int* __restrict__ bsum,
                                                    int* __restrict__ row_ptr,
                                                    int* __restrict__ cursor) {
  int i = blockIdx.x * 256 + threadIdx.x;
  if (i >= N_NODES) return;
  int ex = row_ptr[i] + bsum[blockIdx.x];
  row_ptr[i] = ex;
  cursor[i] = ex;
  if (i == N_NODES - 1) row_ptr[N_NODES] = ex + counts[i];
}

__global__ void scatter_kernel(const int* __restrict__ rows, const int* __restrict__ cols,
                               const float* __restrict__ vals, int* __restrict__ cursor,
                               int* __restrict__ col_s, float* __restrict__ val_s) {
  int i = blockIdx.x * blockDim.x + threadIdx.x;
  int stride = gridDim.x * blockDim.x;
  for (; i < N_EDGES; i += stride) {
    int r = rows[i];
    int pos = atomicAdd(&cursor[r], 1);
    col_s[pos] = cols[i];
    val_s[pos] = vals[i];
  }
}

// entity f32 -> bf16, 8 elems/thread
__global__ __launch_bounds__(256) void tobf16_kernel(const float* __restrict__ src,
                                                     unsigned short* __restrict__ dst,
                                                     int n8) {
  int i = blockIdx.x * blockDim.x + threadIdx.x;
  if (i >= n8) return;
  float4 a = *(const float4*)&src[i * 8];
  float4 b = *(const float4*)&src[i * 8 + 4];
  u16x8 o;
  o[0] = f2bf(a.x); o[1] = f2bf(a.y); o[2] = f2bf(a.z); o[3] = f2bf(a.w);
  o[4] = f2bf(b.x); o[5] = f2bf(b.y); o[6] = f2bf(b.z); o[7] = f2bf(b.w);
  *(u16x8*)&dst[i * 8] = o;
}

// one wave per row: agg[r][:] = sum_e val[e] * x[col[e]][:]  (x in bf16, acc fp32)
__global__ __launch_bounds__(256) void agg_kernel(const unsigned short* __restrict__ xb,
                                                  const int* __restrict__ row_ptr,
                                                  const int* __restrict__ cols,
                                                  const float* __restrict__ vals,
                                                  float* __restrict__ agg) {
  int wid = threadIdx.x >> 6;
  int lane = threadIdx.x & 63;
  int r = blockIdx.x * 4 + wid;
  if (r >= N_NODES) return;
  int e0 = row_ptr[r], e1 = row_ptr[r + 1];
  float ax = 0.f, ay = 0.f;
  int e = e0;
  for (; e + 1 < e1; e += 2) {
    int c0 = cols[e], c1 = cols[e + 1];
    float v0 = vals[e], v1 = vals[e + 1];
    ushort2 x0 = *(const ushort2*)&xb[c0 * D + lane * 2];
    ushort2 x1 = *(const ushort2*)&xb[c1 * D + lane * 2];
    ax = fmaf(v0, bf2f(x0.x), ax);
    ay = fmaf(v0, bf2f(x0.y), ay);
    ax = fmaf(v1, bf2f(x1.x), ax);
    ay = fmaf(v1, bf2f(x1.y), ay);
  }
  if (e < e1) {
    int c = cols[e];
    float v = vals[e];
    ushort2 xv = *(const ushort2*)&xb[c * D + lane * 2];
    ax = fmaf(v, bf2f(xv.x), ax);
    ay = fmaf(v, bf2f(xv.y), ay);
  }
  float2 o = {ax, ay};
  *(float2*)&agg[r * D + lane * 2] = o;
}

// Y[r][:] = relu(X[r][:] @ W + b) -> bf16; block: 64 rows x 128 cols, thread: 4 rows x 8 cols
__global__ __launch_bounds__(256) void gemm_layer(const float* __restrict__ X,
                                                  const float* __restrict__ W,
                                                  const float* __restrict__ bias,
                                                  unsigned short* __restrict__ Yb) {
  __shared__ float xT[D][65];  // transposed tile, padded
  int t = threadIdx.x;
  int r0 = blockIdx.x * 64;
#pragma unroll
  for (int it = 0; it < 8; ++it) {
    int fid = it * 256 + t;   // 0..2047 over 64 rows x 32 float4
    int rl = fid >> 5;
    int kq = fid & 31;
    float4 g = {0.f, 0.f, 0.f, 0.f};
    int r = r0 + rl;
    if (r < N_NODES) g = *(const float4*)&X[r * D + kq * 4];
    xT[kq * 4 + 0][rl] = g.x;
    xT[kq * 4 + 1][rl] = g.y;
    xT[kq * 4 + 2][rl] = g.z;
    xT[kq * 4 + 3][rl] = g.w;
  }
  __syncthreads();
  int tx = t & 15;   // col group: cols tx*8 .. tx*8+7
  int ty = t >> 4;   // rows r0 + ty + {0,16,32,48}
  float acc[4][8] = {};
#pragma unroll 4
  for (int k = 0; k < D; ++k) {
    float4 w0 = *(const float4*)&W[k * D + tx * 8];
    float4 w1 = *(const float4*)&W[k * D + tx * 8 + 4];
    float wv[8] = {w0.x, w0.y, w0.z, w0.w, w1.x, w1.y, w1.z, w1.w};
    float xv[4];
#pragma unroll
    for (int i = 0; i < 4; ++i) xv[i] = xT[k][ty + 16 * i];
#pragma unroll
    for (int i = 0; i < 4; ++i)
#pragma unroll
      for (int j = 0; j < 8; ++j) acc[i][j] = fmaf(xv[i], wv[j], acc[i][j]);
  }
  float bb[8];
#pragma unroll
  for (int j = 0; j < 8; ++j) bb[j] = bias[tx * 8 + j];
#pragma unroll
  for (int i = 0; i < 4; ++i) {
    int r = r0 + ty + 16 * i;
    if (r < N_NODES) {
      u16x8 o;
#pragma unroll
      for (int j = 0; j < 8; ++j) o[j] = f2bf(fmaxf(acc[i][j] + bb[j], 0.f));
      *(u16x8*)&Yb[r * D + tx * 8] = o;
    }
  }
}

// transpose+convert fc_W [KDIM][N_ENT] f32 -> Wt [N_ENT][KDIM] bf16
__global__ __launch_bounds__(256) void wt_kernel(const float* __restrict__ fcW,
                                                 unsigned short* __restrict__ Wt) {
  int n = blockIdx.x * 256 + threadIdx.x;
  int k0 = blockIdx.y * 8;
  if (n >= N_ENT) return;
  u16x8 pk;
#pragma unroll
  for (int e = 0; e < 8; ++e) pk[e] = f2bf(fcW[(size_t)(k0 + e) * N_ENT + n]);
  *(u16x8*)&Wt[(size_t)n * KDIM + k0] = pk;
}

// ebf[b][k] bf16: k<128 -> xb[head_idx[b]][k] (already bf16), else f2bf(rel_table[rel_ids[b]][k-128])
__global__ __launch_bounds__(256) void gather_bf16(const unsigned short* __restrict__ xb,
                                                   const float* __restrict__ rel_table,
                                                   const int* __restrict__ head_idx,
                                                   const int* __restrict__ rel_ids,
                                                   unsigned short* __restrict__ ebf) {
  int b = blockIdx.x;
  int k = threadIdx.x;
  unsigned short v;
  if (k < D) v = xb[head_idx[b] * D + k];
  else       v = f2bf(rel_table[rel_ids[b] * D + (k - D)]);
  ebf[b * KDIM + k] = v;
}

// FC: out[b][n] = sum_k ebf[b][k]*Wt[n][k] + fcb[n]
// 1024 thr = 16 waves (4 wrow x 4 wcol); block tile 256b x 256n; wave tile 64b x 64n
__global__ __launch_bounds__(1024) void fc_mfma(const unsigned short* __restrict__ ebf,
                                                const unsigned short* __restrict__ Wt,
                                                const float* __restrict__ fcb,
                                                float* __restrict__ out) {
  int t = threadIdx.x;
  int lane = t & 63;
  int wave = t >> 6;
  int wrow = wave >> 2;   // 0..3
  int wcol = wave & 3;    // 0..3
  int b_wave = blockIdx.y * 256 + wrow * 64;
  int n_wave = blockIdx.x * 256 + wcol * 64;

  int l16 = lane & 15;
  int lq = lane >> 4;  // 0..3

  f32x4 acc[4][4];
#pragma unroll
  for (int m = 0; m < 4; ++m)
#pragma unroll
    for (int nt = 0; nt < 4; ++nt) acc[m][nt] = (f32x4){0.f, 0.f, 0.f, 0.f};

  const unsigned short* aBase = ebf + (b_wave + l16) * KDIM + lq * 8;
  const unsigned short* bBase[4];
#pragma unroll
  for (int nt = 0; nt < 4; ++nt) {
    int n = n_wave + nt * 16 + l16;
    int nn = n < N_ENT ? n : N_ENT - 1;  // clamp; stores guarded below
    bBase[nt] = Wt + (size_t)nn * KDIM + lq * 8;
  }

#pragma unroll
  for (int kk = 0; kk < 8; ++kk) {
    bf16x8 bb[4];
#pragma unroll
    for (int nt = 0; nt < 4; ++nt)
      bb[nt] = *(const bf16x8*)(bBase[nt] + kk * 32);
#pragma unroll
    for (int m = 0; m < 4; ++m) {
      bf16x8 a = *(const bf16x8*)(aBase + m * 16 * KDIM + kk * 32);
#pragma unroll
      for (int nt = 0; nt < 4; ++nt)
        acc[m][nt] = __builtin_amdgcn_mfma_f32_16x16x32_bf16(a, bb[nt], acc[m][nt], 0, 0, 0);
    }
  }

#pragma unroll
  for (int nt = 0; nt < 4; ++nt) {
    int n = n_wave + nt * 16 + l16;
    if (n >= N_ENT) continue;
    float bv = fcb[n];
#pragma unroll
    for (int m = 0; m < 4; ++m) {
      int brow = b_wave + m * 16 + lq * 4;
#pragma unroll
      for (int r = 0; r < 4; ++r)
        out[(size_t)(brow + r) * N_ENT + n] = acc[m][nt][r] + bv;
    }
  }
}

extern "C" void kernel_launch(void* const* d_in, const int* in_sizes, int n_in,
                              void* d_out, int out_size, void* d_ws, size_t ws_size,
                              hipStream_t stream) {
  const float* entity    = (const float*)d_in[0];
  const float* edge_val  = (const float*)d_in[1];
  const float* gnn_W     = (const float*)d_in[2];
  const float* gnn_b     = (const float*)d_in[3];
  const float* rel_table = (const float*)d_in[4];
  const float* fc_W      = (const float*)d_in[5];
  const float* fc_b      = (const float*)d_in[6];
  const int* edge_row    = (const int*)d_in[7];
  const int* edge_col    = (const int*)d_in[8];
  const int* head_idx    = (const int*)d_in[9];
  const int* rel_ids     = (const int*)d_in[10];
  float* out = (float*)d_out;

  char* ws = (char*)d_ws;
  size_t off = 0;
  auto alloc = [&](size_t bytes) -> void* {
    void* p = ws + off;
    off = (off + bytes + 255) & ~(size_t)255;
    return p;
  };
  int* counts   = (int*)alloc((size_t)N_NODES * 4);
  int* row_ptr  = (int*)alloc((size_t)(N_NODES + 1) * 4);
  int* cursor   = (int*)alloc((size_t)N_NODES * 4);
  int* bsum     = (int*)alloc((size_t)256 * 4);
  int* col_s    = (int*)alloc((size_t)N_EDGES * 4);
  float* val_s  = (float*)alloc((size_t)N_EDGES * 4);
  float* agg    = (float*)alloc((size_t)N_NODES * D * 4);   // fp32; reused as Wt after layers
  unsigned short* xbuf  = (unsigned short*)alloc((size_t)N_NODES * D * 2);  // bf16
  unsigned short* entbf = (unsigned short*)alloc((size_t)N_NODES * D * 2);  // bf16
  unsigned short* ebf   = (unsigned short*)alloc((size_t)BATCH * KDIM * 2);

  unsigned short* Wt = (unsigned short*)agg;  // 50000*256*2 = 25.6 MB == agg size

  // CSR build (row structure is layer-invariant)
  zero_i32<<<(N_NODES + 255) / 256, 256, 0, stream>>>(counts, N_NODES);
  hist_kernel<<<1024, 256, 0, stream>>>(edge_row, counts);
  scan1_kernel<<<SCAN_BLOCKS, 256, 0, stream>>>(counts, row_ptr, bsum);
  scan2_kernel<<<1, 256, 0, stream>>>(bsum);
  scan3_kernel<<<SCAN_BLOCKS, 256, 0, stream>>>(counts, bsum, row_ptr, cursor);
  scatter_kernel<<<1024, 256, 0, stream>>>(edge_row, edge_col, edge_val, cursor, col_s, val_s);

  // entity -> bf16
  tobf16_kernel<<<(N_NODES * D / 8 + 255) / 256, 256, 0, stream>>>(entity, entbf, N_NODES * D / 8);

  // 5 GNN layers (x propagated in bf16)
  for (int layer = 0; layer < N_LAYERS; ++layer) {
    const unsigned short* xin = (layer == 0) ? entbf : xbuf;
    agg_kernel<<<N_NODES / 4, 256, 0, stream>>>(xin, row_ptr, col_s, val_s, agg);
    gemm_layer<<<(N_NODES + 63) / 64, 256, 0, stream>>>(agg, gnn_W + (size_t)layer * D * D,
                                                        gnn_b + (size_t)layer * D, xbuf);
  }

  // W transpose+bf16 (into agg's space) and embed gather+concat in bf16
  dim3 wtg((N_ENT + 255) / 256, KDIM / 8);
  wt_kernel<<<wtg, 256, 0, stream>>>(fc_W, Wt);
  gather_bf16<<<BATCH, KDIM, 0, stream>>>(xbuf, rel_table, head_idx, rel_ids, ebf);

  // FC: [1024,256] @ [256,50000] + b via bf16 MFMA, 256x256 block tile
  dim3 fcg((N_ENT + 255) / 256, BATCH / 256);
  fc_mfma<<<fcg, 1024, 0, stream>>>(ebf, Wt, fc_b, out);
}

// Round 4
// 531.111 us; speedup vs baseline: 2.3889x; 1.4031x over previous
//
#include <hip/hip_runtime.h>

// GNN (5 layers sparse msg-passing + dense+relu) -> gather -> concat -> FC over 50000 entities.
// CSR built once per call (hist + distributed scan + scatter).
// Node features + agg propagated in bf16; all GEMMs are bf16 MFMA with fp32 accum.
// FC: LDS-staged swizzled B-tile, 16 b-chunk loop, store-bound epilogue.

#define N_NODES 50000
#define N_EDGES 800000
#define D 128
#define N_LAYERS 5
#define N_ENT 50000
#define BATCH 1024
#define KDIM 256  // 2*D
#define SCAN_BLOCKS ((N_NODES + 255) / 256)  // 196
#define FC_NT 128

typedef __attribute__((ext_vector_type(8))) __bf16 bf16x8;
typedef __attribute__((ext_vector_type(4))) float f32x4;
typedef __attribute__((ext_vector_type(8))) unsigned short u16x8;

__device__ inline unsigned short f2bf(float x) {
  unsigned int u = __float_as_uint(x);
  unsigned int r = (u + 0x7FFFu + ((u >> 16) & 1u)) >> 16;  // RNE
  return (unsigned short)r;
}
__device__ inline float bf2f(unsigned short b) {
  return __uint_as_float(((unsigned int)b) << 16);
}

__global__ void zero_i32(int* __restrict__ p, int n) {
  int i = blockIdx.x * blockDim.x + threadIdx.x;
  if (i < n) p[i] = 0;
}

__global__ void hist_kernel(const int* __restrict__ rows, int* __restrict__ counts) {
  int i = blockIdx.x * blockDim.x + threadIdx.x;
  int stride = gridDim.x * blockDim.x;
  for (; i < N_EDGES; i += stride) atomicAdd(&counts[rows[i]], 1);
}

__device__ inline int block_exscan256(int v, int* wsum, int* tot) {
  int t = threadIdx.x, lane = t & 63, wid = t >> 6;
  int s = v;
#pragma unroll
  for (int off = 1; off < 64; off <<= 1) {
    int u = __shfl_up(s, off, 64);
    if (lane >= off) s += u;
  }
  if (lane == 63) wsum[wid] = s;
  __syncthreads();
  if (t == 0) {
    int run = 0;
#pragma unroll
    for (int w = 0; w < 4; ++w) { int tmp = wsum[w]; wsum[w] = run; run += tmp; }
    wsum[4] = run;
  }
  __syncthreads();
  *tot = wsum[4];
  return wsum[wid] + s - v;
}

__global__ __launch_bounds__(256) void scan1_kernel(const int* __restrict__ counts,
                                                    int* __restrict__ row_ptr,
                                                    int* __restrict__ bsum) {
  __shared__ int wsum[5];
  int i = blockIdx.x * 256 + threadIdx.x;
  int v = (i < N_NODES) ? counts[i] : 0;
  int tot;
  int ex = block_exscan256(v, wsum, &tot);
  if (i < N_NODES) row_ptr[i] = ex;
  if (threadIdx.x == 0) bsum[blockIdx.x] = tot;
}

__global__ __launch_bounds__(256) void scan2_kernel(int* __restrict__ bsum) {
  __shared__ int wsum[5];
  int t = threadIdx.x;
  int v = (t < SCAN_BLOCKS) ? bsum[t] : 0;
  int tot;
  int ex = block_exscan256(v, wsum, &tot);
  if (t < SCAN_BLOCKS) bsum[t] = ex;
}

__global__ __launch_bounds__(256) void scan3_kernel(const int* __restrict__ counts,
                                                    const int* __restrict__ bsum,
                                                    int* __restrict__ row_ptr,
                                                    int* __restrict__ cursor) {
  int i = blockIdx.x * 256 + threadIdx.x;
  if (i >= N_NODES) return;
  int ex = row_ptr[i] + bsum[blockIdx.x];
  row_ptr[i] = ex;
  cursor[i] = ex;
  if (i == N_NODES - 1) row_ptr[N_NODES] = ex + counts[i];
}

__global__ void scatter_kernel(const int* __restrict__ rows, const int* __restrict__ cols,
                               const float* __restrict__ vals, int* __restrict__ cursor,
                               int* __restrict__ col_s, float* __restrict__ val_s) {
  int i = blockIdx.x * blockDim.x + threadIdx.x;
  int stride = gridDim.x * blockDim.x;
  for (; i < N_EDGES; i += stride) {
    int r = rows[i];
    int pos = atomicAdd(&cursor[r], 1);
    col_s[pos] = cols[i];
    val_s[pos] = vals[i];
  }
}

__global__ __launch_bounds__(256) void tobf16_kernel(const float* __restrict__ src,
                                                     unsigned short* __restrict__ dst,
                                                     int n8) {
  int i = blockIdx.x * blockDim.x + threadIdx.x;
  if (i >= n8) return;
  float4 a = *(const float4*)&src[i * 8];
  float4 b = *(const float4*)&src[i * 8 + 4];
  u16x8 o;
  o[0] = f2bf(a.x); o[1] = f2bf(a.y); o[2] = f2bf(a.z); o[3] = f2bf(a.w);
  o[4] = f2bf(b.x); o[5] = f2bf(b.y); o[6] = f2bf(b.z); o[7] = f2bf(b.w);
  *(u16x8*)&dst[i * 8] = o;
}

// one wave per row: aggb[r][:] = bf16( sum_e val[e] * x[col[e]][:] )
// edge (col,val) loaded lane-parallel (1 instr per 64 edges), broadcast via shfl,
// 8 independent x-row gathers in flight per step.
__global__ __launch_bounds__(256) void agg_kernel(const unsigned short* __restrict__ xb,
                                                  const int* __restrict__ row_ptr,
                                                  const int* __restrict__ cols,
                                                  const float* __restrict__ vals,
                                                  unsigned short* __restrict__ aggb) {
  int wid = threadIdx.x >> 6;
  int lane = threadIdx.x & 63;
  int r = blockIdx.x * 4 + wid;
  if (r >= N_NODES) return;
  int e0 = row_ptr[r], e1 = row_ptr[r + 1];
  float ax = 0.f, ay = 0.f;
  for (int base = e0; base < e1; base += 64) {
    int idx = base + lane;
    bool ok = idx < e1;
    int cl = ok ? cols[idx] : 0;
    float vl = ok ? vals[idx] : 0.f;
    int cnt = min(64, e1 - base);
    int j = 0;
    for (; j + 8 <= cnt; j += 8) {
      int c[8]; float v[8]; ushort2 xv[8];
#pragma unroll
      for (int q = 0; q < 8; ++q) { c[q] = __shfl(cl, j + q); v[q] = __shfl(vl, j + q); }
#pragma unroll
      for (int q = 0; q < 8; ++q) xv[q] = *(const ushort2*)&xb[c[q] * D + lane * 2];
#pragma unroll
      for (int q = 0; q < 8; ++q) {
        ax = fmaf(v[q], bf2f(xv[q].x), ax);
        ay = fmaf(v[q], bf2f(xv[q].y), ay);
      }
    }
    for (; j < cnt; ++j) {
      int c = __shfl(cl, j); float v = __shfl(vl, j);
      ushort2 xv0 = *(const ushort2*)&xb[c * D + lane * 2];
      ax = fmaf(v, bf2f(xv0.x), ax);
      ay = fmaf(v, bf2f(xv0.y), ay);
    }
  }
  ushort2 o = {f2bf(ax), f2bf(ay)};
  *(ushort2*)&aggb[r * D + lane * 2] = o;
}

// gnn_W [L][k][j] f32 -> Wt5 [L][j][k] bf16
__global__ void wconv_kernel(const float* __restrict__ gW, unsigned short* __restrict__ Wt5) {
  int idx = blockIdx.x * 256 + threadIdx.x;
  if (idx >= N_LAYERS * D * D) return;
  int l = idx / (D * D);
  int rem = idx - l * D * D;
  int j = rem >> 7;
  int k = rem & 127;
  Wt5[idx] = f2bf(gW[l * D * D + k * D + j]);
}

// Yb = relu(Ab @ W + b) in bf16 MFMA; block: 64 rows x 128 cols, 4 waves (32 cols each)
__global__ __launch_bounds__(256) void gemm_mfma(const unsigned short* __restrict__ Ab,
                                                 const unsigned short* __restrict__ Bt,  // [j][k] bf16
                                                 const float* __restrict__ bias,
                                                 unsigned short* __restrict__ Yb) {
  int t = threadIdx.x, lane = t & 63, wave = t >> 6;
  int l16 = lane & 15, lq = lane >> 4;
  int r0 = blockIdx.x * 64;
  int nbase = wave * 32;
  f32x4 acc[4][2];
#pragma unroll
  for (int m = 0; m < 4; ++m) { acc[m][0] = (f32x4){0,0,0,0}; acc[m][1] = (f32x4){0,0,0,0}; }
#pragma unroll
  for (int kk = 0; kk < 4; ++kk) {
    bf16x8 bfr[2];
#pragma unroll
    for (int nt = 0; nt < 2; ++nt)
      bfr[nt] = *(const bf16x8*)&Bt[(nbase + nt * 16 + l16) * D + kk * 32 + lq * 8];
#pragma unroll
    for (int m = 0; m < 4; ++m) {
      bf16x8 a = *(const bf16x8*)&Ab[(size_t)(r0 + m * 16 + l16) * D + kk * 32 + lq * 8];
      acc[m][0] = __builtin_amdgcn_mfma_f32_16x16x32_bf16(a, bfr[0], acc[m][0], 0, 0, 0);
      acc[m][1] = __builtin_amdgcn_mfma_f32_16x16x32_bf16(a, bfr[1], acc[m][1], 0, 0, 0);
    }
  }
#pragma unroll
  for (int nt = 0; nt < 2; ++nt) {
    int col = nbase + nt * 16 + l16;
    float bb = bias[col];
#pragma unroll
    for (int m = 0; m < 4; ++m) {
      int row = r0 + m * 16 + lq * 4;
#pragma unroll
      for (int r = 0; r < 4; ++r)
        if (row + r < N_NODES)
          Yb[(size_t)(row + r) * D + col] = f2bf(fmaxf(acc[m][nt][r] + bb, 0.f));
    }
  }
}

// transpose+convert fc_W [KDIM][N_ENT] f32 -> Wt [N_ENT][KDIM] bf16
__global__ __launch_bounds__(256) void wt_kernel(const float* __restrict__ fcW,
                                                 unsigned short* __restrict__ Wt) {
  int n = blockIdx.x * 256 + threadIdx.x;
  int k0 = blockIdx.y * 8;
  if (n >= N_ENT) return;
  u16x8 pk;
#pragma unroll
  for (int e = 0; e < 8; ++e) pk[e] = f2bf(fcW[(size_t)(k0 + e) * N_ENT + n]);
  *(u16x8*)&Wt[(size_t)n * KDIM + k0] = pk;
}

__global__ __launch_bounds__(256) void gather_bf16(const unsigned short* __restrict__ xb,
                                                   const float* __restrict__ rel_table,
                                                   const int* __restrict__ head_idx,
                                                   const int* __restrict__ rel_ids,
                                                   unsigned short* __restrict__ ebf) {
  int b = blockIdx.x;
  int k = threadIdx.x;
  unsigned short v;
  if (k < D) v = xb[head_idx[b] * D + k];
  else       v = f2bf(rel_table[rel_ids[b] * D + (k - D)]);
  ebf[b * KDIM + k] = v;
}

// FC: out[b][n] = sum_k ebf[b][k]*Wt[n][k] + fcb[n]
// block: n-tile 128, 4 waves (32 cols each); B staged in LDS (swizzled); loop 16 b-chunks of 64
__global__ __launch_bounds__(256) void fc_mfma(const unsigned short* __restrict__ ebf,
                                               const unsigned short* __restrict__ Wt,
                                               const float* __restrict__ fcb,
                                               float* __restrict__ out) {
  __shared__ unsigned short wtile[FC_NT * KDIM];  // 64 KB
  int t = threadIdx.x;
  int lane = t & 63, wave = t >> 6;
  int l16 = lane & 15, lq = lane >> 4;
  int n0 = blockIdx.x * FC_NT;

  // stage Wt[n0..n0+127][:] -> LDS, 16B-chunk swizzle: chunk ^= (row & 7)
  const char* wsrc = (const char*)(Wt + (size_t)n0 * KDIM);
  char* wdst = (char*)wtile;
#pragma unroll
  for (int it = 0; it < 16; ++it) {
    int c = it * 256 + t;  // 16B chunk id, 0..4095
    int row = c >> 5;      // 512 B per row
    int ci = c & 31;
    float4 v = *(const float4*)(wsrc + (size_t)c * 16);
    *(float4*)(wdst + row * 512 + ((ci ^ (row & 7)) * 16)) = v;
  }
  __syncthreads();

  int ncol[2]; float bv[2];
#pragma unroll
  for (int nt = 0; nt < 2; ++nt) {
    int n = n0 + wave * 32 + nt * 16 + l16;
    ncol[nt] = n;
    bv[nt] = (n < N_ENT) ? fcb[n] : 0.f;
  }

  for (int bc = 0; bc < 16; ++bc) {
    int b0 = bc * 64;
    f32x4 acc[4][2];
#pragma unroll
    for (int m = 0; m < 4; ++m) { acc[m][0] = (f32x4){0,0,0,0}; acc[m][1] = (f32x4){0,0,0,0}; }
#pragma unroll
    for (int kk = 0; kk < 8; ++kk) {
      bf16x8 bfr[2];
#pragma unroll
      for (int nt = 0; nt < 2; ++nt) {
        int row_n = wave * 32 + nt * 16 + l16;
        bfr[nt] = *(const bf16x8*)(wdst + row_n * 512 + (((lq + kk * 4) ^ (row_n & 7)) * 16));
      }
#pragma unroll
      for (int m = 0; m < 4; ++m) {
        bf16x8 a = *(const bf16x8*)&ebf[(b0 + m * 16 + l16) * KDIM + kk * 32 + lq * 8];
        acc[m][0] = __builtin_amdgcn_mfma_f32_16x16x32_bf16(a, bfr[0], acc[m][0], 0, 0, 0);
        acc[m][1] = __builtin_amdgcn_mfma_f32_16x16x32_bf16(a, bfr[1], acc[m][1], 0, 0, 0);
      }
    }
#pragma unroll
    for (int nt = 0; nt < 2; ++nt) {
      if (ncol[nt] < N_ENT) {
#pragma unroll
        for (int m = 0; m < 4; ++m) {
          int brow = b0 + m * 16 + lq * 4;
#pragma unroll
          for (int r = 0; r < 4; ++r)
            out[(size_t)(brow + r) * N_ENT + ncol[nt]] = acc[m][nt][r] + bv[nt];
        }
      }
    }
  }
}

extern "C" void kernel_launch(void* const* d_in, const int* in_sizes, int n_in,
                              void* d_out, int out_size, void* d_ws, size_t ws_size,
                              hipStream_t stream) {
  const float* entity    = (const float*)d_in[0];
  const float* edge_val  = (const float*)d_in[1];
  const float* gnn_W     = (const float*)d_in[2];
  const float* gnn_b     = (const float*)d_in[3];
  const float* rel_table = (const float*)d_in[4];
  const float* fc_W      = (const float*)d_in[5];
  const float* fc_b      = (const float*)d_in[6];
  const int* edge_row    = (const int*)d_in[7];
  const int* edge_col    = (const int*)d_in[8];
  const int* head_idx    = (const int*)d_in[9];
  const int* rel_ids     = (const int*)d_in[10];
  float* out = (float*)d_out;

  char* ws = (char*)d_ws;
  size_t off = 0;
  auto alloc = [&](size_t bytes) -> void* {
    void* p = ws + off;
    off = (off + bytes + 255) & ~(size_t)255;
    return p;
  };
  int* counts   = (int*)alloc((size_t)N_NODES * 4);
  int* row_ptr  = (int*)alloc((size_t)(N_NODES + 1) * 4);
  int* cursor   = (int*)alloc((size_t)N_NODES * 4);
  int* bsum     = (int*)alloc((size_t)256 * 4);
  int* col_s    = (int*)alloc((size_t)N_EDGES * 4);
  float* val_s  = (float*)alloc((size_t)N_EDGES * 4);
  unsigned short* aggb  = (unsigned short*)alloc((size_t)N_NODES * D * 2);
  unsigned short* xbuf  = (unsigned short*)alloc((size_t)N_NODES * D * 2);
  unsigned short* entbf = (unsigned short*)alloc((size_t)N_NODES * D * 2);
  unsigned short* ebf   = (unsigned short*)alloc((size_t)BATCH * KDIM * 2);
  unsigned short* Wt    = (unsigned short*)alloc((size_t)N_ENT * KDIM * 2);
  unsigned short* Wt5   = (unsigned short*)alloc((size_t)N_LAYERS * D * D * 2);

  // CSR build (row structure is layer-invariant)
  zero_i32<<<(N_NODES + 255) / 256, 256, 0, stream>>>(counts, N_NODES);
  hist_kernel<<<1024, 256, 0, stream>>>(edge_row, counts);
  scan1_kernel<<<SCAN_BLOCKS, 256, 0, stream>>>(counts, row_ptr, bsum);
  scan2_kernel<<<1, 256, 0, stream>>>(bsum);
  scan3_kernel<<<SCAN_BLOCKS, 256, 0, stream>>>(counts, bsum, row_ptr, cursor);
  scatter_kernel<<<1024, 256, 0, stream>>>(edge_row, edge_col, edge_val, cursor, col_s, val_s);

  // conversions
  tobf16_kernel<<<(N_NODES * D / 8 + 255) / 256, 256, 0, stream>>>(entity, entbf, N_NODES * D / 8);
  wconv_kernel<<<(N_LAYERS * D * D + 255) / 256, 256, 0, stream>>>(gnn_W, Wt5);

  // 5 GNN layers (x in bf16)
  for (int layer = 0; layer < N_LAYERS; ++layer) {
    const unsigned short* xin = (layer == 0) ? entbf : xbuf;
    agg_kernel<<<N_NODES / 4, 256, 0, stream>>>(xin, row_ptr, col_s, val_s, aggb);
    gemm_mfma<<<(N_NODES + 63) / 64, 256, 0, stream>>>(aggb, Wt5 + (size_t)layer * D * D,
                                                       gnn_b + (size_t)layer * D, xbuf);
  }

  // FC weight transpose + embed gather
  dim3 wtg((N_ENT + 255) / 256, KDIM / 8);
  wt_kernel<<<wtg, 256, 0, stream>>>(fc_W, Wt);
  gather_bf16<<<BATCH, KDIM, 0, stream>>>(xbuf, rel_table, head_idx, rel_ids, ebf);

  // FC
  fc_mfma<<<(N_ENT + FC_NT - 1) / FC_NT, 256, 0, stream>>>(ebf, Wt, fc_b, out);
}